// Round 6
// baseline (1035.071 us; speedup 1.0000x reference)
//
#include <hip/hip_runtime.h>
#include <hip/hip_fp16.h>

#define NT 25
#define NXY 448
#define NPIX (448*448)
#define NTOT (NT*NPIX)
#define PXY 115
#define SXY 111

#define TW 32
#define TH 8

// s_w layout offsets (floats)
#define W1R 0
#define W1I 300
#define W2R 600
#define W2I 1032
#define B1R 1464
#define B1I 1476
#define B2R 1488
#define B2I 1500
#define W3R 1512
#define W3I 1524
#define B3R 1536

// ---------------- K1: fused complex conv1(1->12,5x5)+ReLU -> conv2(12->12,3 temporal)+ReLU
// -> conv3(12->1) real part = denR ; p_re = x_re - denR*relu(tau)/niter
// OUT: float32, real part only, C-order [25,448,448]; writes p_re*relu(p_w)
__global__ __launch_bounds__(256) void k_conv(
    const float* __restrict__ re, const float* __restrict__ im,
    const float* __restrict__ w1r, const float* __restrict__ w1i,
    const float* __restrict__ b1r, const float* __restrict__ b1i,
    const float* __restrict__ w2r, const float* __restrict__ w2i,
    const float* __restrict__ b2r, const float* __restrict__ b2i,
    const float* __restrict__ w3r, const float* __restrict__ w3i,
    const float* __restrict__ b3r,
    const float* __restrict__ tau_w, const float* __restrict__ p_w,
    const int* __restrict__ num_iter,
    float* __restrict__ out)
{
    __shared__ float s_w[1537];
    __shared__ float s_inR[12][36];
    __shared__ float s_inI[12][36];
    __shared__ __half2 s_h1[3][12][TH*TW];

    const int tid = threadIdx.x;
    const int tx = tid & 31;     // col within tile (Y, contiguous)
    const int ty = tid >> 5;     // row within tile (X)
    const int Y0 = blockIdx.x * TW;
    const int X0 = blockIdx.y * TH;

    for (int i = tid; i < 300; i += 256) { s_w[W1R+i] = w1r[i]; s_w[W1I+i] = w1i[i]; }
    for (int i = tid; i < 432; i += 256) { s_w[W2R+i] = w2r[i]; s_w[W2I+i] = w2i[i]; }
    if (tid < 12) {
        s_w[B1R+tid] = b1r[tid]; s_w[B1I+tid] = b1i[tid];
        s_w[B2R+tid] = b2r[tid]; s_w[B2I+tid] = b2i[tid];
        s_w[W3R+tid] = w3r[tid]; s_w[W3I+tid] = w3i[tid];
    }
    if (tid == 0) { s_w[B3R] = b3r[0]; }

    const float tsc = fmaxf(tau_w[0], 0.f) / (float)num_iter[0];
    const float pwv = fmaxf(p_w[0], 0.f);

    for (int tf = 0; tf <= NT; ++tf) {
        if (tf < NT) {
            // stage input frame tf with 2-halo (zero-padded borders, SAME conv)
            for (int idx = tid; idx < 12*36; idx += 256) {
                int r = idx / 36, c = idx % 36;
                int gx = X0 + r - 2, gy = Y0 + c - 2;
                bool ok = (gx >= 0) && (gx < NXY) && (gy >= 0) && (gy < NXY);
                int cgx = ok ? gx : 0, cgy = ok ? gy : 0;
                size_t a = (size_t)tf * NPIX + (size_t)cgx * NXY + cgy;
                float vr = re[a], vi = im[a];
                s_inR[r][c] = ok ? vr : 0.f;
                s_inI[r][c] = ok ? vi : 0.f;
            }
        }
        __syncthreads();
        if (tf < NT) {
            // conv1 for my pixel, 12 complex channels
            float aR[12], aI[12];
            #pragma unroll
            for (int c = 0; c < 12; ++c) { aR[c] = s_w[B1R+c]; aI[c] = s_w[B1I+c]; }
            #pragma unroll 1
            for (int ky = 0; ky < 5; ++ky) {
                #pragma unroll
                for (int kx = 0; kx < 5; ++kx) {
                    float xr = s_inR[ty+ky][tx+kx];
                    float xi = s_inI[ty+ky][tx+kx];
                    #pragma unroll
                    for (int c = 0; c < 12; ++c) {
                        float wr = s_w[W1R + c*25 + ky*5 + kx];
                        float wi = s_w[W1I + c*25 + ky*5 + kx];
                        aR[c] += xr*wr - xi*wi;
                        aI[c] += xr*wi + xi*wr;
                    }
                }
            }
            int slot = tf % 3;
            #pragma unroll
            for (int c = 0; c < 12; ++c)
                s_h1[slot][c][tid] = __floats2half2_rn(fmaxf(aR[c],0.f), fmaxf(aI[c],0.f));
        }
        __syncthreads();
        int tc = tf - 1;
        if (tc >= 0) {
            // conv2 (3-tap temporal, 12->12) + ReLU, then conv3 (12->1) REAL part
            float hR[3][12], hI[3][12];
            #pragma unroll
            for (int dt = 0; dt < 3; ++dt) {
                int tt = tc - 1 + dt;
                if (tt >= 0 && tt < NT) {
                    int sl = tt % 3;
                    #pragma unroll
                    for (int c = 0; c < 12; ++c) {
                        __half2 h = s_h1[sl][c][tid];
                        hR[dt][c] = __low2float(h); hI[dt][c] = __high2float(h);
                    }
                } else {
                    #pragma unroll
                    for (int c = 0; c < 12; ++c) { hR[dt][c] = 0.f; hI[dt][c] = 0.f; }
                }
            }
            float dR = s_w[B3R];
            #pragma unroll 1
            for (int c2 = 0; c2 < 12; ++c2) {
                float zr = s_w[B2R+c2], zi = s_w[B2I+c2];
                #pragma unroll
                for (int dt = 0; dt < 3; ++dt) {
                    #pragma unroll
                    for (int c1 = 0; c1 < 12; ++c1) {
                        float wr = s_w[W2R + (c2*12+c1)*3 + dt];
                        float wi = s_w[W2I + (c2*12+c1)*3 + dt];
                        zr += hR[dt][c1]*wr - hI[dt][c1]*wi;
                        zi += hR[dt][c1]*wi + hI[dt][c1]*wr;
                    }
                }
                zr = fmaxf(zr, 0.f); zi = fmaxf(zi, 0.f);
                dR += zr*s_w[W3R+c2] - zi*s_w[W3I+c2];
            }
            size_t idx = (size_t)tc*NPIX + (size_t)(X0+ty)*NXY + (Y0+tx);
            out[idx] = (re[idx] - dR * tsc) * pwv;
        }
    }
}

// ---------------- K2: Gram matrices G_b = M_b M_b^H  (80 x 5x5 complex Hermitian)
__global__ __launch_bounds__(256) void k_gram(
    const float* __restrict__ re, const float* __restrict__ im,
    float* __restrict__ gG)
{
    const int b = blockIdx.x;            // 0..79  = chunk*16 + i*4 + j
    const int chunk = b >> 4;
    const int pidx = b & 15;
    const int X0 = (pidx >> 2) * SXY;
    const int Y0 = (pidx & 3) * SXY;
    const int tid = threadIdx.x;

    float acc[50];
    #pragma unroll
    for (int k = 0; k < 50; ++k) acc[k] = 0.f;

    const int npx = PXY * PXY;           // 13225
    for (int pi = tid; pi < npx; pi += 256) {
        int px = pi / PXY, py = pi % PXY;
        size_t base = (size_t)(X0 + px) * NXY + (Y0 + py);
        float xr[5], xi[5];
        #pragma unroll
        for (int r = 0; r < 5; ++r) {
            size_t a = (size_t)(chunk*5 + r) * NPIX + base;
            xr[r] = re[a]; xi[r] = im[a];
        }
        #pragma unroll
        for (int t1 = 0; t1 < 5; ++t1)
            #pragma unroll
            for (int t2 = 0; t2 < 5; ++t2) {
                acc[(t1*5+t2)*2]   += xr[t1]*xr[t2] + xi[t1]*xi[t2];
                acc[(t1*5+t2)*2+1] += xi[t1]*xr[t2] - xr[t1]*xi[t2];
            }
    }
    #pragma unroll
    for (int k = 0; k < 50; ++k) {
        float v = acc[k];
        for (int m = 32; m > 0; m >>= 1) v += __shfl_xor(v, m, 64);
        acc[k] = v;
    }
    __shared__ float s_red[4][50];
    int lane = tid & 63, wid = tid >> 6;
    if (lane == 0) {
        #pragma unroll
        for (int k = 0; k < 50; ++k) s_red[wid][k] = acc[k];
    }
    __syncthreads();
    if (tid < 50) {
        gG[b*50 + tid] = s_red[0][tid] + s_red[1][tid] + s_red[2][tid] + s_red[3][tid];
    }
}

// ---------------- K3: 5x5 complex Hermitian Jacobi eigensolve -> W = V f(Lambda) V^H
__global__ void k_eig(const float* __restrict__ gG, const float* __restrict__ thres,
                      float* __restrict__ gW)
{
    int b = blockIdx.x * 64 + threadIdx.x;
    if (b >= 80) return;
    float Ar[5][5], Ai[5][5], Vr[5][5], Vi[5][5];
    #pragma unroll
    for (int a = 0; a < 5; ++a)
        #pragma unroll
        for (int c = 0; c < 5; ++c) {
            Ar[a][c] = gG[b*50 + (a*5+c)*2];
            Ai[a][c] = gG[b*50 + (a*5+c)*2 + 1];
            Vr[a][c] = (a==c) ? 1.f : 0.f;
            Vi[a][c] = 0.f;
        }
    for (int sw = 0; sw < 9; ++sw) {
        #pragma unroll
        for (int p = 0; p < 4; ++p) {
            #pragma unroll
            for (int q = p+1; q < 5; ++q) {
                float apr = Ar[p][q], api = Ai[p][q];
                float n2 = apr*apr + api*api;
                if (n2 > 1e-24f) {
                    float mlen = sqrtf(n2);
                    float phr = apr / mlen, phi = api / mlen;
                    float tau = (Ar[q][q] - Ar[p][p]) / (2.f * mlen);
                    float tt = (tau >= 0.f ? 1.f : -1.f) / (fabsf(tau) + sqrtf(1.f + tau*tau));
                    float cc = 1.f / sqrtf(1.f + tt*tt);
                    float ss = tt * cc;
                    float wr2 = ss * phr, wi2 = ss * phi;   // w = s*e^{i phi}
                    #pragma unroll
                    for (int k = 0; k < 5; ++k) {
                        float xr = Ar[k][p], xi2 = Ai[k][p];
                        float yr = Ar[k][q], yi = Ai[k][q];
                        Ar[k][p] = cc*xr - (wr2*yr + wi2*yi);
                        Ai[k][p] = cc*xi2 - (wr2*yi - wi2*yr);
                        Ar[k][q] = wr2*xr - wi2*xi2 + cc*yr;
                        Ai[k][q] = wr2*xi2 + wi2*xr + cc*yi;
                        float vxr = Vr[k][p], vxi = Vi[k][p];
                        float vyr = Vr[k][q], vyi = Vi[k][q];
                        Vr[k][p] = cc*vxr - (wr2*vyr + wi2*vyi);
                        Vi[k][p] = cc*vxi - (wr2*vyi - wi2*vyr);
                        Vr[k][q] = wr2*vxr - wi2*vxi + cc*vyr;
                        Vi[k][q] = wr2*vxi + wi2*vxr + cc*vyi;
                    }
                    #pragma unroll
                    for (int k = 0; k < 5; ++k) {
                        float xr = Ar[p][k], xi2 = Ai[p][k];
                        float yr = Ar[q][k], yi = Ai[q][k];
                        Ar[p][k] = cc*xr - (wr2*yr - wi2*yi);
                        Ai[p][k] = cc*xi2 - (wr2*yi + wi2*yr);
                        Ar[q][k] = wr2*xr + wi2*xi2 + cc*yr;
                        Ai[q][k] = wr2*xi2 - wi2*xr + cc*yi;
                    }
                }
            }
        }
    }
    float sv[5], s0 = 0.f;
    #pragma unroll
    for (int k = 0; k < 5; ++k) { sv[k] = sqrtf(fmaxf(Ar[k][k], 0.f)); s0 = fmaxf(s0, sv[k]); }
    float th = fmaxf(thres[b], 0.f) * s0;
    float ratio[5];
    #pragma unroll
    for (int k = 0; k < 5; ++k)
        ratio[k] = sv[k] > 0.f ? fmaxf(sv[k] - th, 0.f) / sv[k] : 0.f;
    #pragma unroll
    for (int a = 0; a < 5; ++a)
        #pragma unroll
        for (int c = 0; c < 5; ++c) {
            float wr = 0.f, wi = 0.f;
            #pragma unroll
            for (int k = 0; k < 5; ++k) {
                wr += ratio[k] * (Vr[a][k]*Vr[c][k] + Vi[a][k]*Vi[c][k]);
                wi += ratio[k] * (Vi[a][k]*Vr[c][k] - Vr[a][k]*Vi[c][k]);
            }
            gW[b*50 + (a*5+c)*2]   = wr;
            gW[b*50 + (a*5+c)*2+1] = wi;
        }
}

// ---------------- K3b: region-averaged W (7x7 overlap regions per chunk), includes 1/cnt
__global__ void k_wavg(const float* __restrict__ gW, float* __restrict__ gA)
{
    int blk = blockIdx.x;         // chunk*49 + rx*7 + ry
    int e = threadIdx.x;
    if (e >= 25) return;
    int chunk = blk / 49;
    int rem = blk % 49;
    int rx = rem / 7, ry = rem % 7;
    int i0 = rx >> 1, i1 = (rx + 1) >> 1;
    int j0 = ry >> 1, j1 = (ry + 1) >> 1;
    float sr = 0.f, si = 0.f; int cnt = 0;
    for (int i = i0; i <= i1; ++i)
        for (int j = j0; j <= j1; ++j) {
            int b = chunk*16 + i*4 + j;
            sr += gW[b*50 + e*2];
            si += gW[b*50 + e*2 + 1];
            ++cnt;
        }
    float inv = 1.f / (float)cnt;
    gA[blk*50 + e*2]   = sr * inv;
    gA[blk*50 + e*2+1] = si * inv;
}

// ---------------- K4: q_re = Re(Wavg * x5) ; out += q_re*(1-p_w)   (fp32 RMW)
__global__ __launch_bounds__(256) void k_final(
    const float* __restrict__ re, const float* __restrict__ im,
    const float* __restrict__ gA, const float* __restrict__ p_w,
    float* __restrict__ out)
{
    int pix = blockIdx.x * 256 + threadIdx.x;
    int chunk = blockIdx.y;
    int X = pix / NXY, Y = pix % NXY;
    int i_lo = (X - 4) / SXY; if (i_lo < 0) i_lo = 0;
    int i_hi = X / SXY;       if (i_hi > 3) i_hi = 3;
    int j_lo = (Y - 4) / SXY; if (j_lo < 0) j_lo = 0;
    int j_hi = Y / SXY;       if (j_hi > 3) j_hi = 3;
    int rx = i_lo + i_hi, ry = j_lo + j_hi;
    const float* wa = gA + (size_t)(chunk*49 + rx*7 + ry) * 50;
    float Wr[5][5], Wi[5][5];
    #pragma unroll
    for (int a = 0; a < 5; ++a)
        #pragma unroll
        for (int r = 0; r < 5; ++r) {
            Wr[a][r] = wa[(a*5+r)*2];
            Wi[a][r] = wa[(a*5+r)*2+1];
        }
    float xr[5], xi[5];
    #pragma unroll
    for (int r = 0; r < 5; ++r) {
        size_t a = (size_t)(chunk*5+r)*NPIX + pix;
        xr[r] = re[a]; xi[r] = im[a];
    }
    float qwv = 1.f - p_w[0];
    #pragma unroll
    for (int tl = 0; tl < 5; ++tl) {
        float qr = 0.f;
        #pragma unroll
        for (int r = 0; r < 5; ++r)
            qr += Wr[tl][r]*xr[r] - Wi[tl][r]*xi[r];
        size_t idx = (size_t)(chunk*5+tl)*NPIX + pix;
        out[idx] += qr*qwv;
    }
}

extern "C" void kernel_launch(void* const* d_in, const int* in_sizes, int n_in,
                              void* d_out, int out_size, void* d_ws, size_t ws_size,
                              hipStream_t stream)
{
    const float* re    = (const float*)d_in[0];
    const float* im    = (const float*)d_in[1];
    const float* w1r   = (const float*)d_in[2];
    const float* w1i   = (const float*)d_in[3];
    const float* b1r   = (const float*)d_in[4];
    const float* b1i   = (const float*)d_in[5];
    const float* w2r   = (const float*)d_in[6];
    const float* w2i   = (const float*)d_in[7];
    const float* b2r   = (const float*)d_in[8];
    const float* b2i   = (const float*)d_in[9];
    const float* w3r   = (const float*)d_in[10];
    const float* w3i   = (const float*)d_in[11];
    const float* b3r   = (const float*)d_in[12];
    const float* thres = (const float*)d_in[14];
    const float* tau_w = (const float*)d_in[15];
    const float* p_w   = (const float*)d_in[16];
    const int* num_iter= (const int*)d_in[17];

    float* ws = (float*)d_ws;
    float* gG = ws;                 // 80*50 floats
    float* gW = gG + 80*50;         // 80*50 floats
    float* gA = gW + 80*50;         // 245*50 floats  (total ~81 KB)

    float* outf = (float*)d_out;

    dim3 g1(NXY/TW, NXY/TH);
    k_conv<<<g1, 256, 0, stream>>>(re, im, w1r, w1i, b1r, b1i, w2r, w2i,
                                   b2r, b2i, w3r, w3i, b3r,
                                   tau_w, p_w, num_iter, outf);
    k_gram<<<80, 256, 0, stream>>>(re, im, gG);
    k_eig<<<2, 64, 0, stream>>>(gG, thres, gW);
    k_wavg<<<245, 32, 0, stream>>>(gW, gA);
    dim3 g4(NPIX/256, 5);
    k_final<<<g4, 256, 0, stream>>>(re, im, gA, p_w, outf);
}